// Round 1
// 370.368 us; speedup vs baseline: 1.0659x; 1.0659x over previous
//
#include <hip/hip_runtime.h>

// 18-wire, 3-layer batched statevector sim. Intermediate state = PACKED bf16
// (re | im<<16) in one uint32 per amplitude, ping-ponged between d_in[0] and
// d_in[1]. Compute is fp32, amplitudes held as f32x2 (re,im) VGPR pairs and
// gates done with packed VOP3P (v_pk_fma_f32/v_pk_mul_f32): 6 instructions
// per RY+RZ pair instead of 12 scalar — halves gate code size (I$ relief)
// and VALU issue. bf16 pack happens BEFORE the T2 transpose (commutes), so
// T2 moves one packed uint32 plane (40 DS ops) instead of two float planes
// (80). All layouts, addressing, CNOT suffix-xor folding and the B1 in-place
// trick are unchanged from the 394 µs version. Zero __syncthreads anywhere.

#define LROW 36u           // LDS row stride in floats (144B, 16B-aligned skew)
#define LDSW 2304u         // per-wave LDS floats (64 rows * 36)

typedef float f32x2 __attribute__((ext_vector_type(2)));

static __device__ __forceinline__ float rfl(float x) {
    return __int_as_float(__builtin_amdgcn_readfirstlane(__float_as_int(x)));
}

static __device__ __forceinline__ f32x2 unpk(unsigned u) {
    f32x2 v;
    v.x = __uint_as_float(u << 16);
    v.y = __uint_as_float(u & 0xFFFF0000u);
    return v;
}

static __device__ __forceinline__ unsigned packbf(f32x2 a) {  // RNE
    unsigned ua = __float_as_uint(a.x); ua += 0x7FFFu + ((ua >> 16) & 1u);
    unsigned ub = __float_as_uint(a.y); ub += 0x7FFFu + ((ub >> 16) & 1u);
    return (ua >> 16) | (ub & 0xFFFF0000u);
}

// RY+RZ on an amplitude pair (RZ global phase dropped), packed fp32 VOP3P.
// ry = {c, s} in an SGPR pair, pz = {pc, ps} in an SGPR pair (broadcast via
// op_sel). Math identical to the scalar version:
//   t0 = c*a0 - s*a1 ; t1 = s*a0 + c*a1 ; a1' = pc*t1 -/+ ps*swap(t1)
static __device__ __forceinline__ void sq_pair2(f32x2& a0, f32x2& a1,
                                                f32x2 ry, f32x2 pz) {
    f32x2 m, n, t1, p;
    asm("v_pk_mul_f32 %0, %1, %2 op_sel:[1,0] op_sel_hi:[1,1]"       // m = s*a1
        : "=v"(m) : "s"(ry), "v"(a1));
    asm("v_pk_mul_f32 %0, %1, %2 op_sel:[0,0] op_sel_hi:[0,1]"       // n = c*a1
        : "=v"(n) : "s"(ry), "v"(a1));
    asm("v_pk_fma_f32 %0, %1, %2, %3 op_sel:[1,0,0] op_sel_hi:[1,1,1]"  // t1 = s*a0 + n
        : "=v"(t1) : "s"(ry), "v"(a0), "v"(n));
    asm("v_pk_fma_f32 %0, %1, %0, %2 op_sel:[0,0,0] op_sel_hi:[0,1,1] neg_lo:[0,0,1] neg_hi:[0,0,1]"
        : "+v"(a0) : "s"(ry), "v"(m));                                // a0 = c*a0 - m
    asm("v_pk_mul_f32 %0, %1, %2 op_sel:[1,1] op_sel_hi:[1,0]"       // p = ps * t1.yx
        : "=v"(p) : "s"(pz), "v"(t1));
    asm("v_pk_fma_f32 %0, %1, %2, %3 op_sel:[0,0,0] op_sel_hi:[0,1,1] neg_lo:[0,0,1] neg_hi:[0,0,0]"
        : "=v"(a1) : "s"(pz), "v"(t1), "v"(p));                       // a1 = pc*t1 -+ p
}

template<int J>
__device__ __forceinline__ void sqg2(f32x2* a, f32x2 ry, f32x2 pz) {
#pragma unroll
    for (int r = 0; r < 32; ++r) {
        if (((r >> J) & 1) == 0) {
            sq_pair2(a[r], a[r + (1 << J)], ry, pz);
        }
    }
}

// T1: float-plane transpose, both planes sequentially through one buffer.
// value (g,c) -> row layout via tb; read row l contiguous. Banks <=2-way.
static __device__ __forceinline__ void t1_float(f32x2* a, float* Lb, int l, unsigned tb) {
#pragma unroll
    for (int g = 0; g < 8; ++g)
#pragma unroll
        for (int c = 0; c < 4; ++c)
            Lb[tb + g * 288 + c * 36] = a[4*g+c].x;
#pragma unroll
    for (int q = 0; q < 8; ++q) {
        const float4 v = *(const float4*)&Lb[(unsigned)l * LROW + (q << 2)];
        a[4*q+0].x = v.x; a[4*q+1].x = v.y; a[4*q+2].x = v.z; a[4*q+3].x = v.w;
    }
#pragma unroll
    for (int g = 0; g < 8; ++g)
#pragma unroll
        for (int c = 0; c < 4; ++c)
            Lb[tb + g * 288 + c * 36] = a[4*g+c].y;
#pragma unroll
    for (int q = 0; q < 8; ++q) {
        const float4 v = *(const float4*)&Lb[(unsigned)l * LROW + (q << 2)];
        a[4*q+0].y = v.x; a[4*q+1].y = v.y; a[4*q+2].y = v.z; a[4*q+3].y = v.w;
    }
}

// pack to bf16 FIRST (commutes with transpose), then T2 on one uint32 plane:
// write row l contiguous (uint4), read scatter back to (g,c) layout.
static __device__ __forceinline__ void pack_t2(f32x2* a, float* Lb, int l, unsigned tb,
                                               unsigned v[8][4]) {
    unsigned* Lu = (unsigned*)Lb;
#pragma unroll
    for (int q = 0; q < 8; ++q) {
        uint4 pv;
        pv.x = packbf(a[4*q+0]); pv.y = packbf(a[4*q+1]);
        pv.z = packbf(a[4*q+2]); pv.w = packbf(a[4*q+3]);
        *(uint4*)&Lu[(unsigned)l * LROW + (q << 2)] = pv;
    }
#pragma unroll
    for (int g = 0; g < 8; ++g)
#pragma unroll
        for (int c = 0; c < 4; ++c)
            v[g][c] = Lu[tb + g * 288 + c * 36];
}

// ---------------- passB common gate/transpose body ----------------
// Wave coords: lanes l = [L5..L0] = [m17,m16,m12,m11,m3,m2]; regs idx = [m15..13 | m1,m0].
struct BCoef2 { f32x2 RY[7], PZ[7]; };

static __device__ __forceinline__ void passB_coefs(BCoef2& k, const float* pl) {
#pragma unroll
    for (int j = 0; j < 7; ++j) {
        const int w = 6 - j;
        float sv, cv;
        __sincosf(0.5f * pl[w], &sv, &cv);
        k.RY[j].x = rfl(cv); k.RY[j].y = rfl(sv);
        __sincosf(pl[18 + w], &sv, &cv);
        k.PZ[j].x = rfl(cv); k.PZ[j].y = rfl(sv);
    }
}

static __device__ __forceinline__ void passB_body(f32x2* a, float* Lb,
                                                  const BCoef2& k, int l) {
    const unsigned tb = (unsigned)(l & 1) * 144u + (unsigned)(l >> 1);
    // phase 1: idx bits [4:2] = m15,m14,m13 -> coeff idx 4,3,2
    sqg2<4>(a, k.RY[4], k.PZ[4]);
    sqg2<3>(a, k.RY[3], k.PZ[3]);
    sqg2<2>(a, k.RY[2], k.PZ[2]);
    t1_float(a, Lb, l, tb);   // after T1: idx2 = [m17,m16,m12,m11,m3]
    // phase 2: idx2 [4]=m17(k6) [3]=m16(k5) [2]=m12(k1) [1]=m11(k0)
    sqg2<4>(a, k.RY[6], k.PZ[6]);
    sqg2<3>(a, k.RY[5], k.PZ[5]);
    sqg2<2>(a, k.RY[1], k.PZ[1]);
    sqg2<1>(a, k.RY[0], k.PZ[0]);
}

// passB_1: fp32 planes -> packed bf16 in u (== (unsigned*)re plane), UNPERMUTED store.
// NOTE: re and u alias by design — no __restrict__ on them.
__global__ __launch_bounds__(128) void passB1_k(const float* re, const float* im,
                                                unsigned* u, const float* __restrict__ params)
{
    __shared__ float lds[2 * LDSW];
    const int t   = threadIdx.x;
    const int l   = t & 63;
    const int wib = t >> 6;
    float* Lb = lds + wib * LDSW;
    const int wv  = ((int)blockIdx.x << 1) | wib;
    const int b   = wv >> 7;
    const int mid = wv & 127;
    const int L5 = (l >> 5) & 1, L4 = (l >> 4) & 1, L3 = (l >> 3) & 1, L2 = (l >> 2) & 1;
    const int L1 = (l >> 1) & 1, L0 = l & 1;

    const unsigned base = ((unsigned)b << 18) | ((unsigned)mid << 4);
    const unsigned sel  = (L5 << 17) | (L4 << 16) | (L3 << 12) | (L2 << 11) | (L1 << 3) | (L0 << 2);

    f32x2 a[32];
#pragma unroll
    for (int g = 0; g < 8; ++g) {
        const unsigned n = base + sel + ((unsigned)g << 13);
        const float4 vr = *(const float4*)&re[n];
        const float4 vi = *(const float4*)&im[n];
        a[4*g+0].x = vr.x; a[4*g+0].y = vi.x;
        a[4*g+1].x = vr.y; a[4*g+1].y = vi.y;
        a[4*g+2].x = vr.z; a[4*g+2].y = vi.z;
        a[4*g+3].x = vr.w; a[4*g+3].y = vi.w;
    }

    BCoef2 k; passB_coefs(k, params);          // layer 0
    passB_body(a, Lb, k, l);

    unsigned v[8][4];
    pack_t2(a, Lb, l, (unsigned)L0 * 144u + (unsigned)(l >> 1), v);

    // UNPERMUTED store (perm deferred to A_1's block relabel): in-place safe.
#pragma unroll
    for (int g = 0; g < 8; ++g) {
        const int h = (L5 << 6) | (L4 << 5) | (g << 2) | (L3 << 1) | L2;
        const unsigned n = base + ((unsigned)h << 11) + (L1 << 3) + (L0 << 2);
        *(uint4*)&u[n] = make_uint4(v[g][0], v[g][1], v[g][2], v[g][3]);
    }
}

// passB layers 1,2: packed bf16 src -> packed bf16 dst (ping-pong), perm materialized.
__global__ __launch_bounds__(128) void passBk_k(const unsigned* __restrict__ src,
                                                unsigned* __restrict__ dst,
                                                const float* __restrict__ params, int layer)
{
    __shared__ float lds[2 * LDSW];
    const int t   = threadIdx.x;
    const int l   = t & 63;
    const int wib = t >> 6;
    float* Lb = lds + wib * LDSW;
    const int wv  = ((int)blockIdx.x << 1) | wib;
    const int b   = wv >> 7;
    const int mid = wv & 127;
    const int L5 = (l >> 5) & 1, L4 = (l >> 4) & 1, L3 = (l >> 3) & 1, L2 = (l >> 2) & 1;
    const int L1 = (l >> 1) & 1, L0 = l & 1;

    const unsigned base = ((unsigned)b << 18) | ((unsigned)mid << 4);
    const unsigned sel  = (L5 << 17) | (L4 << 16) | (L3 << 12) | (L2 << 11) | (L1 << 3) | (L0 << 2);

    f32x2 a[32];
#pragma unroll
    for (int g = 0; g < 8; ++g) {
        const unsigned n = base + sel + ((unsigned)g << 13);
        const uint4 pv = *(const uint4*)&src[n];
        a[4*g+0] = unpk(pv.x);
        a[4*g+1] = unpk(pv.y);
        a[4*g+2] = unpk(pv.z);
        a[4*g+3] = unpk(pv.w);
    }

    BCoef2 k; passB_coefs(k, params + layer * 36);
    passB_body(a, Lb, k, l);

    unsigned v[8][4];
    pack_t2(a, Lb, l, (unsigned)L0 * 144u + (unsigned)(l >> 1), v);

    // permuted store: h = [m17..m11], x = suffix-xor(h)
#pragma unroll
    for (int g = 0; g < 8; ++g) {
        int h = (L5 << 6) | (L4 << 5) | (g << 2) | (L3 << 1) | L2;
        int x = h ^ (h >> 1); x ^= x >> 2; x ^= x >> 4;
        const unsigned n = base + ((unsigned)x << 11) + (L1 << 3) + (L0 << 2);
        *(uint4*)&dst[n] = make_uint4(v[g][0], v[g][1], v[g][2], v[g][3]);
    }
}

// ---------------- passA: window bits 0..10 (one wave) ----------------
// Lanes l = m7..2; regs idx = [m10..8 | m1,m0]. Fixed: batch + hi7 = n17..11.
// FIRST: loads use physical block hi7p = L ^ (L>>1)  (B_1's deferred perm).
template<bool FIRST, bool FINAL>
__global__ __launch_bounds__(128) void passA_k(const unsigned* __restrict__ src,
                                               unsigned* __restrict__ dst,
                                               const float* __restrict__ params, int layer,
                                               const float* __restrict__ hw,
                                               const float* __restrict__ hb,
                                               float* __restrict__ out)
{
    __shared__ float lds[2 * LDSW];
    const int t   = threadIdx.x;
    const int l   = t & 63;
    const int wib = t >> 6;
    float* Lb = lds + wib * LDSW;
    const int wv  = ((int)blockIdx.x << 1) | wib;
    const int b   = wv >> 7;
    const int L   = wv & 127;                       // logical hi7
    const int hip = FIRST ? (L ^ (L >> 1)) : L;     // physical hi7 for loads
    const int n11 = L & 1;
    const unsigned baseL = ((unsigned)b << 18) | ((unsigned)hip << 11);
    const unsigned baseS = ((unsigned)b << 18) | ((unsigned)L << 11);

    // issue all loads first (addresses cheap), coefs + quad gates hide the drain
    uint4 U[8];
#pragma unroll
    for (int g = 0; g < 8; ++g)
        U[g] = *(const uint4*)&src[baseL + ((unsigned)g << 8) + ((unsigned)l << 2)];

    // coefs: idx p (0..10) <-> wire 17-p ; {c,s}/{pc,ps} as SGPR pairs
    f32x2 RY2[11], PZ2[11];
    const float* pl = params + layer * 36;
#pragma unroll
    for (int p = 0; p < 11; ++p) {
        const int w = 17 - p;
        float sv, cv;
        __sincosf(0.5f * pl[w], &sv, &cv);
        RY2[p].x = rfl(cv); RY2[p].y = rfl(sv);
        __sincosf(pl[18 + w], &sv, &cv);
        PZ2[p].x = rfl(cv); PZ2[p].y = rfl(sv);
    }

    f32x2 a[32];
    // per-quad: unpack + quad-local gates SQ(1),SQ(0) as each load lands
#pragma unroll
    for (int g = 0; g < 8; ++g) {
        a[4*g+0] = unpk(U[g].x);
        a[4*g+1] = unpk(U[g].y);
        a[4*g+2] = unpk(U[g].z);
        a[4*g+3] = unpk(U[g].w);
        sq_pair2(a[4*g+0], a[4*g+2], RY2[1], PZ2[1]);  // m1
        sq_pair2(a[4*g+1], a[4*g+3], RY2[1], PZ2[1]);
        sq_pair2(a[4*g+0], a[4*g+1], RY2[0], PZ2[0]);  // m0
        sq_pair2(a[4*g+2], a[4*g+3], RY2[0], PZ2[0]);
    }

    // cross-quad phase 1: SQ(10),SQ(9),SQ(8) on idx bits 4..2
    sqg2<4>(a, RY2[10], PZ2[10]);
    sqg2<3>(a, RY2[9],  PZ2[9]);
    sqg2<2>(a, RY2[8],  PZ2[8]);

    // lane-gate SQ(7): m7 = lane bit 5, partner = shfl_xor 32
    {
        const int side   = (l >> 5) & 1;
        const float c7   = RY2[7].x;
        const float bco  = side ? RY2[7].y : -RY2[7].y;
        const float qc   = side ? PZ2[7].x : 1.f;
        const float qs   = side ? PZ2[7].y : 0.f;
#pragma unroll
        for (int r = 0; r < 32; ++r) {
            const float pr = __shfl_xor(a[r].x, 32);
            const float pi = __shfl_xor(a[r].y, 32);
            const float tr = fmaf(c7, a[r].x, bco * pr);
            const float ti = fmaf(c7, a[r].y, bco * pi);
            a[r].x = fmaf(qc, tr, -(qs * ti));
            a[r].y = fmaf(qc, ti,  (qs * tr));
        }
    }

    // T1: value (g,c) -> row (g<<3)|(m7<<2)|c, pos = l&31  (banks <=2-way: free)
    const unsigned tb = (unsigned)((l >> 5) & 1) * 144u + (unsigned)(l & 31);
    t1_float(a, Lb, l, tb);   // after T1: idx2 = m6..2

    // phase 2: idx2 bit j = m(j+2): SQ(6..2)
    sqg2<4>(a, RY2[6], PZ2[6]);
    sqg2<3>(a, RY2[5], PZ2[5]);
    sqg2<2>(a, RY2[4], PZ2[4]);
    sqg2<1>(a, RY2[3], PZ2[3]);
    sqg2<0>(a, RY2[2], PZ2[2]);

    const int msk = n11 ? 0x1FF : 0;

    if (!FINAL) {
        unsigned v[8][4];
        pack_t2(a, Lb, l, tb, v);
        // chain C(11,10)..(1,0) folded into store address: out = sxor(m10..2) ^ msk
#pragma unroll
        for (int g = 0; g < 8; ++g) {
            int h = (g << 6) | l;
            int x = h ^ (h >> 1); x ^= x >> 2; x ^= x >> 4; x ^= x >> 8;
            x ^= msk;
            const int y = x & 1;  // in-quad permutation select
            uint4 pv;
            pv.x = y ? v[g][2] : v[g][0];
            pv.y = y ? v[g][3] : v[g][1];
            pv.z = y ? v[g][1] : v[g][3];
            pv.w = y ? v[g][0] : v[g][2];
            *(uint4*)&dst[baseS + ((unsigned)x << 2)] = pv;
        }
    } else {
        // float T2 back to (g,c) layout, then expval + head
#pragma unroll
        for (int q = 0; q < 8; ++q)
            *(float4*)&Lb[(unsigned)l * LROW + (q << 2)] =
                make_float4(a[4*q+0].x, a[4*q+1].x, a[4*q+2].x, a[4*q+3].x);
#pragma unroll
        for (int g = 0; g < 8; ++g)
#pragma unroll
            for (int c = 0; c < 4; ++c)
                a[4*g+c].x = Lb[tb + g * 288 + c * 36];
#pragma unroll
        for (int q = 0; q < 8; ++q)
            *(float4*)&Lb[(unsigned)l * LROW + (q << 2)] =
                make_float4(a[4*q+0].y, a[4*q+1].y, a[4*q+2].y, a[4*q+3].y);
#pragma unroll
        for (int g = 0; g < 8; ++g)
#pragma unroll
            for (int c = 0; c < 4; ++c)
                a[4*g+c].y = Lb[tb + g * 288 + c * 36];

        // expval + head (probabilities permutation-invariant; signs use cascaded bits)
        float Ghi = 0.f;
#pragma unroll
        for (int j = 0; j < 7; ++j) {   // bits 11..17 <-> wires 6..0
            const float wv_ = hw[6 - j];
            Ghi += ((L >> j) & 1) ? -wv_ : wv_;
        }
        float acc = 0.f;
#pragma unroll
        for (int g = 0; g < 8; ++g) {
            int h = (g << 6) | l;
            int x = h ^ (h >> 1); x ^= x >> 2; x ^= x >> 4; x ^= x >> 8;
            x ^= msk;
            const float q0 = fmaf(a[4*g+0].x, a[4*g+0].x, a[4*g+0].y * a[4*g+0].y);
            const float q1 = fmaf(a[4*g+1].x, a[4*g+1].x, a[4*g+1].y * a[4*g+1].y);
            const float q2 = fmaf(a[4*g+2].x, a[4*g+2].x, a[4*g+2].y * a[4*g+2].y);
            const float q3 = fmaf(a[4*g+3].x, a[4*g+3].x, a[4*g+3].y * a[4*g+3].y);
            const float psum = (q0 + q1) + (q2 + q3);
            const float d1   = (q0 + q1) - (q2 + q3);
            const float d0   = (q0 - q1) - (q2 - q3);
            float Gm = 0.f;
#pragma unroll
            for (int j = 0; j < 9; ++j) {   // x bit j = out_{j+2} <-> wire 15-j
                const float wv_ = hw[15 - j];
                Gm += ((x >> j) & 1) ? -wv_ : wv_;
            }
            const float ys = (x & 1) ? -1.f : 1.f;
            acc += psum * (Ghi + Gm) + ys * fmaf(d1, hw[16], d0 * hw[17]);
        }
        if (L == 0 && l == 0) acc += hb[0];
#pragma unroll
        for (int off = 32; off > 0; off >>= 1) acc += __shfl_xor(acc, off);
        if (l == 0) atomicAdd(&out[b], acc);
    }
}

extern "C" void kernel_launch(void* const* d_in, const int* in_sizes, int n_in,
                              void* d_out, int out_size, void* d_ws, size_t ws_size,
                              hipStream_t stream)
{
    const float* re0    = (const float*)d_in[0];
    const float* im0    = (const float*)d_in[1];
    unsigned* u0        = (unsigned*)d_in[0];   // packed bf16 state, ping
    unsigned* u1        = (unsigned*)d_in[1];   // packed bf16 state, pong
    const float* params = (const float*)d_in[2];
    const float* hw     = (const float*)d_in[3];
    const float* hb     = (const float*)d_in[4];
    float* out          = (float*)d_out;
    (void)in_sizes; (void)n_in; (void)d_ws; (void)ws_size;

    hipMemsetAsync(out, 0, (size_t)out_size * sizeof(float), stream);

    const dim3 grid(4096), blk(128);
    passB1_k             <<<grid, blk, 0, stream>>>(re0, im0, u0, params);
    passA_k<true,  false><<<grid, blk, 0, stream>>>(u0, u1, params, 0, nullptr, nullptr, nullptr);
    passBk_k             <<<grid, blk, 0, stream>>>(u1, u0, params, 1);
    passA_k<false, false><<<grid, blk, 0, stream>>>(u0, u1, params, 1, nullptr, nullptr, nullptr);
    passBk_k             <<<grid, blk, 0, stream>>>(u1, u0, params, 2);
    passA_k<false, true ><<<grid, blk, 0, stream>>>(u0, nullptr, params, 2, hw, hb, out);
}